// Round 1
// 360.344 us; speedup vs baseline: 1.0280x; 1.0280x over previous
//
#include <hip/hip_runtime.h>
#include <stdint.h>

// ROISelect: B=128 batches, N=131072 anchors, K=256 top-k + ROI gather.
// Single HBM pass over score. Stage1: per-(batch,split) block keeps its 16K
// chunk in registers, LDS-histograms order-preserving uint32 (top 12 bits),
// finds local top-256 bucket threshold, compacts candidate keys
// (value<<32 | N-1-idx) to global scratch. Stage2 (512 thr): per-batch block
// register-stages candidates, selects survivors via LDS histogram, bitonic
// sorts top-P, gathers ROI rows.
//
// NOTE (theory journal): measured dur_us includes ~2x 1GiB harness
// workspace-poison fills (~160us each @84% HBM peak, rocprof top-5) that our
// kernel_launch does not enqueue. Controllable kernel time est. ~50us.

#define BATCH   128
#define NANCH   131072
#define KSEL    256
#define SPLITS  8
#define CHUNK   (NANCH / SPLITS)     // 16384
#define TPB     256
#define V4PT    (CHUNK / TPB / 4)    // 16 float4 per thread (64 floats)
#define NBUCK   4096
#define CAPMAX  8192                 // per-batch candidate capacity (keys)
#define SORTCAP 2048
#define TPB2    512
#define RPT2    (CAPMAX / TPB2)      // 16 register-staged keys / thread

typedef unsigned long long ull;

__device__ __forceinline__ unsigned ord_of(float f) {
    unsigned u = __float_as_uint(f);
    // monotone map: larger float -> larger uint
    return (u & 0x80000000u) ? ~u : (u | 0x80000000u);
}
__device__ __forceinline__ float f_of_ord(unsigned o) {
    unsigned u = (o & 0x80000000u) ? (o ^ 0x80000000u) : ~o;
    return __uint_as_float(u);
}

// wave64 inclusive prefix sum (lane i gets sum of lanes [0,i])
__device__ __forceinline__ int wave_incl_prefix(int v, int lane) {
#pragma unroll
    for (int off = 1; off < 64; off <<= 1) {
        int n = __shfl_up(v, off);
        if (lane >= off) v += n;
    }
    return v;
}
// wave64 inclusive suffix sum (lane i gets sum of lanes [i,63])
__device__ __forceinline__ int wave_incl_suffix(int v, int lane) {
#pragma unroll
    for (int off = 1; off < 64; off <<= 1) {
        int n = __shfl_down(v, off);
        if (lane + off < 64) v += n;
    }
    return v;
}

// ---------------------------------------------------------------- stage 1
__global__ __launch_bounds__(TPB) void topk_stage1(
    const float* __restrict__ score, ull* __restrict__ cand,
    int* __restrict__ cnt, int cap)
{
    __shared__ int hist[NBUCK];
    __shared__ int wtot[TPB / 64];
    __shared__ int s_bstar;
    __shared__ int s_base;

    const int t    = threadIdx.x;
    const int lane = t & 63;
    const int wid  = t >> 6;
    const int sp   = blockIdx.x;   // split within batch row
    const int b    = blockIdx.y;   // batch

    // coalesced float4 loads; whole chunk lives in registers (64 VGPRs)
    const float4* src = (const float4*)(score + (size_t)b * NANCH + (size_t)sp * CHUNK);
    float4 v[V4PT];
#pragma unroll
    for (int i = 0; i < V4PT; ++i) v[i] = src[i * TPB + t];

    for (int i = t; i < NBUCK; i += TPB) hist[i] = 0;
    __syncthreads();

#pragma unroll
    for (int i = 0; i < V4PT; ++i) {
        atomicAdd(&hist[ord_of(v[i].x) >> 20], 1);
        atomicAdd(&hist[ord_of(v[i].y) >> 20], 1);
        atomicAdd(&hist[ord_of(v[i].z) >> 20], 1);
        atomicAdd(&hist[ord_of(v[i].w) >> 20], 1);
    }
    __syncthreads();

    // per-thread partial over its 16-bucket group, then block suffix scan
    // via wave shuffles (2 barriers instead of 16)
    int ps = 0;
#pragma unroll
    for (int p = 0; p < 16; ++p) ps += hist[t * 16 + p];
    int sfx = wave_incl_suffix(ps, lane);
    if (lane == 0) wtot[wid] = sfx;     // wave total
    __syncthreads();
    int hi = 0;
#pragma unroll
    for (int w = 0; w < TPB / 64; ++w) if (w > wid) hi += wtot[w];
    const int sinc = sfx + hi;          // inclusive suffix over block groups

    // largest bucket b* with suffix-count S(b*) >= KSEL  (unique crossing)
    {
        int running = sinc - ps;        // suffix of groups strictly above mine
#pragma unroll
        for (int p = 15; p >= 0; --p) {
            int nr = running + hist[t * 16 + p];
            if (nr >= KSEL && running < KSEL) s_bstar = t * 16 + p;
            running = nr;
        }
    }
    __syncthreads();
    const unsigned thr = (unsigned)s_bstar << 20;   // qualify iff ordered >= thr

    // count qualifiers per thread
    int qc = 0;
#pragma unroll
    for (int i = 0; i < V4PT; ++i) {
        qc += (ord_of(v[i].x) >= thr);
        qc += (ord_of(v[i].y) >= thr);
        qc += (ord_of(v[i].z) >= thr);
        qc += (ord_of(v[i].w) >= thr);
    }
    // block inclusive prefix scan via wave shuffles
    int pfx = wave_incl_prefix(qc, lane);
    if (lane == 63) wtot[wid] = pfx;    // wave total (barrier above guards reuse)
    __syncthreads();
    int lo = 0, total = 0;
#pragma unroll
    for (int w = 0; w < TPB / 64; ++w) {
        total += wtot[w];
        if (w < wid) lo += wtot[w];
    }
    if (t == 0) s_base = atomicAdd(&cnt[b], total);
    __syncthreads();

    int pos = s_base + lo + pfx - qc;   // exclusive position
    ull* cb = cand + (size_t)b * cap;
    const int nbase = sp * CHUNK;
#pragma unroll
    for (int i = 0; i < V4PT; ++i) {
        const int n0 = nbase + 4 * (i * TPB + t);
        unsigned o;
        o = ord_of(v[i].x);
        if (o >= thr && pos < cap) { cb[pos++] = ((ull)o << 32) | (unsigned)(NANCH - 1 - n0); }
        o = ord_of(v[i].y);
        if (o >= thr && pos < cap) { cb[pos++] = ((ull)o << 32) | (unsigned)(NANCH - 2 - n0); }
        o = ord_of(v[i].z);
        if (o >= thr && pos < cap) { cb[pos++] = ((ull)o << 32) | (unsigned)(NANCH - 3 - n0); }
        o = ord_of(v[i].w);
        if (o >= thr && pos < cap) { cb[pos++] = ((ull)o << 32) | (unsigned)(NANCH - 4 - n0); }
    }
}

// ---------------------------------------------------------------- stage 2
__global__ __launch_bounds__(TPB2) void topk_stage2(
    const ull* __restrict__ cand, const int* __restrict__ cnt,
    const float* __restrict__ roi, float* __restrict__ out_roi,
    float* __restrict__ out_score, int cap)
{
    __shared__ int hist[NBUCK];
    __shared__ int wtot[TPB2 / 64];
    __shared__ ull buf[SORTCAP];
    __shared__ int s_bstar, s_csel;

    const int t    = threadIdx.x;
    const int lane = t & 63;
    const int wid  = t >> 6;
    const int b    = blockIdx.x;
    const int c    = min(cnt[b], cap);
    const ull* cb  = cand + (size_t)b * cap;

    // single coalesced global pass: stage candidates into registers
    // (static indexing only — runtime-indexed reg arrays spill to scratch)
    ull rk[RPT2];
#pragma unroll
    for (int q = 0; q < RPT2; ++q) {
        const int i = t + q * TPB2;
        rk[q] = (i < c) ? cb[i] : 0;
    }

    for (int i = t; i < NBUCK; i += TPB2) hist[i] = 0;
    if (t == 0) s_csel = 0;
    __syncthreads();
#pragma unroll
    for (int q = 0; q < RPT2; ++q) {
        if (t + q * TPB2 < c) atomicAdd(&hist[(unsigned)(rk[q] >> 52)], 1);
    }
    __syncthreads();

    // block suffix scan over 8-bucket groups via wave shuffles
    const int G = NBUCK / TPB2;   // 8
    int ps = 0;
#pragma unroll
    for (int p = 0; p < G; ++p) ps += hist[t * G + p];
    int sfx = wave_incl_suffix(ps, lane);
    if (lane == 0) wtot[wid] = sfx;
    __syncthreads();
    int hi = 0;
#pragma unroll
    for (int w = 0; w < TPB2 / 64; ++w) if (w > wid) hi += wtot[w];
    const int sinc = sfx + hi;
    {
        int running = sinc - ps;
#pragma unroll
        for (int p = G - 1; p >= 0; --p) {
            int nr = running + hist[t * G + p];
            if (nr >= KSEL && running < KSEL) s_bstar = t * G + p;
            running = nr;
        }
    }
    __syncthreads();
    const unsigned bstar = (unsigned)s_bstar;

    // compact survivors (bucket >= b*) into LDS from registers
#pragma unroll
    for (int q = 0; q < RPT2; ++q) {
        if (t + q * TPB2 < c && (unsigned)(rk[q] >> 52) >= bstar) {
            int p = atomicAdd(&s_csel, 1);
            if (p < SORTCAP) buf[p] = rk[q];
        }
    }
    __syncthreads();
    const int C = min(s_csel, SORTCAP);
    int P = KSEL;
    while (P < C) P <<= 1;                 // pow2 in [256, 2048]
    for (int i = C + t; i < P; i += TPB2) buf[i] = 0;   // pad (sinks in desc sort)
    __syncthreads();

    // bitonic sort descending on uint64 keys
    for (int kk = 2; kk <= P; kk <<= 1) {
        for (int j = kk >> 1; j > 0; j >>= 1) {
            for (int i = t; i < P; i += TPB2) {
                int ixj = i ^ j;
                if (ixj > i) {
                    ull a = buf[i], d = buf[ixj];
                    bool up = (i & kk) == 0;
                    bool sw = up ? (a < d) : (a > d);
                    if (sw) { buf[i] = d; buf[ixj] = a; }
                }
            }
            __syncthreads();
        }
    }

    // emit in parallel: t<256 gathers ROI rows, 256<=t<512 writes scores
    if (t < KSEL) {
        ull k = buf[t];
        int idx = NANCH - 1 - (int)(unsigned)(k & 0xffffffffull);
        float4 r = ((const float4*)roi)[(size_t)b * NANCH + idx];
        ((float4*)out_roi)[b * KSEL + t] = r;
    } else if (t < 2 * KSEL) {
        const int tt = t - KSEL;
        ull k = buf[tt];
        out_score[b * KSEL + tt] = f_of_ord((unsigned)(k >> 32));
    }
}

// ---------------------------------------------------------------- launch
extern "C" void kernel_launch(void* const* d_in, const int* in_sizes, int n_in,
                              void* d_out, int out_size, void* d_ws, size_t ws_size,
                              hipStream_t stream)
{
    const float* score = (const float*)d_in[0];   // [B, N] fp32
    const float* roi   = (const float*)d_in[1];   // [B, N, 4] fp32
    float* out_roi   = (float*)d_out;                            // [B, K, 4]
    float* out_score = (float*)d_out + (size_t)BATCH * KSEL * 4; // [B, K]

    int* cnt  = (int*)d_ws;                       // [BATCH] counters
    ull* cand = (ull*)((char*)d_ws + 4096);       // [BATCH, cap] keys
    long long avail = ((long long)ws_size - 4096) / (long long)(sizeof(ull) * BATCH);
    int cap = (int)avail;
    if (cap > CAPMAX) cap = CAPMAX;
    if (cap < 1) cap = 1;

    hipMemsetAsync(cnt, 0, BATCH * sizeof(int), stream);
    topk_stage1<<<dim3(SPLITS, BATCH), TPB, 0, stream>>>(score, cand, cnt, cap);
    topk_stage2<<<BATCH, TPB2, 0, stream>>>(cand, cnt, roi, out_roi, out_score, cap);
}

// Round 2
// 356.371 us; speedup vs baseline: 1.0394x; 1.0111x over previous
//
#include <hip/hip_runtime.h>
#include <stdint.h>

// ROISelect: B=128 batches, N=131072 anchors, K=256 top-k + ROI gather.
// Single HBM pass over score. Stage1: per-(batch,split) block stages its 8K
// chunk as order-preserving uint32 in registers, LDS-histograms top 12 bits,
// finds local top-256 bucket threshold, compacts candidate keys
// (ord<<32 | N-1-idx) into a FIXED per-split segment of global scratch and
// writes its exact count (no zero-init, no memset, no global atomics).
// Stage2 (512 thr): per-batch block register-stages the 16 segments,
// re-selects survivors via LDS histogram, bitonic sorts, gathers ROI rows.
//
// THEORY JOURNAL: measured dur_us includes ~2x 1GiB harness workspace-poison
// fills (~160us each @84% HBM peak — the entire rocprof top-5). Structural
// floor ~335us; controllable kernel share this round est. ~25us.

#define BATCH   128
#define NANCH   131072
#define KSEL    256
#define SPLITS  16
#define CHUNK   (NANCH / SPLITS)     // 8192
#define TPB     256
#define V4PT    (CHUNK / TPB / 4)    // 8 uint4 per thread (32 values)
#define NBUCK   4096
#define CAPMAX  8192                 // per-batch candidate capacity (keys)
#define SEGCAP  (CAPMAX / SPLITS)    // 512 per split (expect ~380 used)
#define SORTCAP 2048
#define TPB2    512

typedef unsigned long long ull;

__device__ __forceinline__ unsigned ord_of(float f) {
    unsigned u = __float_as_uint(f);
    // monotone map: larger float -> larger uint
    return (u & 0x80000000u) ? ~u : (u | 0x80000000u);
}
__device__ __forceinline__ float f_of_ord(unsigned o) {
    unsigned u = (o & 0x80000000u) ? (o ^ 0x80000000u) : ~o;
    return __uint_as_float(u);
}

// wave64 inclusive prefix sum (lane i gets sum of lanes [0,i])
__device__ __forceinline__ int wave_incl_prefix(int v, int lane) {
#pragma unroll
    for (int off = 1; off < 64; off <<= 1) {
        int n = __shfl_up(v, off);
        if (lane >= off) v += n;
    }
    return v;
}
// wave64 inclusive suffix sum (lane i gets sum of lanes [i,63])
__device__ __forceinline__ int wave_incl_suffix(int v, int lane) {
#pragma unroll
    for (int off = 1; off < 64; off <<= 1) {
        int n = __shfl_down(v, off);
        if (lane + off < 64) v += n;
    }
    return v;
}

// ---------------------------------------------------------------- stage 1
__global__ __launch_bounds__(TPB) void topk_stage1(
    const float* __restrict__ score, ull* __restrict__ cand,
    int* __restrict__ cnt)
{
    __shared__ int hist[NBUCK];
    __shared__ int wtot[TPB / 64];
    __shared__ int s_bstar;

    const int t    = threadIdx.x;
    const int lane = t & 63;
    const int wid  = t >> 6;
    const int sp   = blockIdx.x;   // split within batch row
    const int b    = blockIdx.y;   // batch

    // coalesced float4 loads; convert to ordered uint ONCE (all later passes
    // read these registers — saves 2 extra ord_of passes)
    const float4* src = (const float4*)(score + (size_t)b * NANCH + (size_t)sp * CHUNK);
    uint4 v[V4PT];
#pragma unroll
    for (int i = 0; i < V4PT; ++i) {
        float4 f = src[i * TPB + t];
        v[i].x = ord_of(f.x); v[i].y = ord_of(f.y);
        v[i].z = ord_of(f.z); v[i].w = ord_of(f.w);
    }

    // zero histogram with vector stores (4 int4 per thread)
    for (int i = t; i < NBUCK / 4; i += TPB) ((int4*)hist)[i] = make_int4(0, 0, 0, 0);
    __syncthreads();

#pragma unroll
    for (int i = 0; i < V4PT; ++i) {
        atomicAdd(&hist[v[i].x >> 20], 1);
        atomicAdd(&hist[v[i].y >> 20], 1);
        atomicAdd(&hist[v[i].z >> 20], 1);
        atomicAdd(&hist[v[i].w >> 20], 1);
    }
    __syncthreads();

    // per-thread partial over its 16-bucket group, block suffix scan via
    // wave shuffles (2 barriers total)
    int ps = 0;
#pragma unroll
    for (int p = 0; p < 16; ++p) ps += hist[t * 16 + p];
    int sfx = wave_incl_suffix(ps, lane);
    if (lane == 0) wtot[wid] = sfx;     // wave total
    __syncthreads();
    int hi = 0;
#pragma unroll
    for (int w = 0; w < TPB / 64; ++w) if (w > wid) hi += wtot[w];
    const int sinc = sfx + hi;          // inclusive suffix over block groups

    // largest bucket b* with suffix-count S(b*) >= KSEL  (unique crossing)
    {
        int running = sinc - ps;        // suffix of groups strictly above mine
#pragma unroll
        for (int p = 15; p >= 0; --p) {
            int nr = running + hist[t * 16 + p];
            if (nr >= KSEL && running < KSEL) s_bstar = t * 16 + p;
            running = nr;
        }
    }
    __syncthreads();
    const unsigned thr = (unsigned)s_bstar << 20;   // qualify iff ordered >= thr

    // count qualifiers per thread
    int qc = 0;
#pragma unroll
    for (int i = 0; i < V4PT; ++i) {
        qc += (v[i].x >= thr);
        qc += (v[i].y >= thr);
        qc += (v[i].z >= thr);
        qc += (v[i].w >= thr);
    }
    // block inclusive prefix scan via wave shuffles
    int pfx = wave_incl_prefix(qc, lane);
    if (lane == 63) wtot[wid] = pfx;    // wave total (s_bstar barrier guards reuse)
    __syncthreads();
    int lo = 0, total = 0;
#pragma unroll
    for (int w = 0; w < TPB / 64; ++w) {
        total += wtot[w];
        if (w < wid) lo += wtot[w];
    }
    // per-(batch,split) count: written unconditionally -> no zero-init needed
    if (t == 0) cnt[b * SPLITS + sp] = (total < SEGCAP) ? total : SEGCAP;

    int pos = lo + pfx - qc;            // exclusive position within segment
    ull* cb = cand + (size_t)b * CAPMAX + (size_t)sp * SEGCAP;
    const int nbase = sp * CHUNK;
#pragma unroll
    for (int i = 0; i < V4PT; ++i) {
        const int n0 = nbase + 4 * (i * TPB + t);
        unsigned o;
        o = v[i].x;
        if (o >= thr && pos < SEGCAP) { cb[pos++] = ((ull)o << 32) | (unsigned)(NANCH - 1 - n0); }
        o = v[i].y;
        if (o >= thr && pos < SEGCAP) { cb[pos++] = ((ull)o << 32) | (unsigned)(NANCH - 2 - n0); }
        o = v[i].z;
        if (o >= thr && pos < SEGCAP) { cb[pos++] = ((ull)o << 32) | (unsigned)(NANCH - 3 - n0); }
        o = v[i].w;
        if (o >= thr && pos < SEGCAP) { cb[pos++] = ((ull)o << 32) | (unsigned)(NANCH - 4 - n0); }
    }
}

// ---------------------------------------------------------------- stage 2
__global__ __launch_bounds__(TPB2) void topk_stage2(
    const ull* __restrict__ cand, const int* __restrict__ cnt,
    const float* __restrict__ roi, float* __restrict__ out_roi,
    float* __restrict__ out_score)
{
    __shared__ int hist[NBUCK];
    __shared__ int wtot[TPB2 / 64];
    __shared__ ull buf[SORTCAP];
    __shared__ int s_bstar, s_csel;

    const int t    = threadIdx.x;
    const int lane = t & 63;
    const int wid  = t >> 6;
    const int b    = blockIdx.x;
    const ull* cb  = cand + (size_t)b * CAPMAX;

    // register-stage all 16 segments: exactly 1 coalesced load / thread / seg
    // (fully unrolled -> static register indexing, no scratch)
    int csp[SPLITS];
    ull rk[SPLITS];
#pragma unroll
    for (int sp = 0; sp < SPLITS; ++sp) {
        int c = cnt[b * SPLITS + sp];
        csp[sp] = (c < SEGCAP) ? c : SEGCAP;
        rk[sp] = (t < csp[sp]) ? cb[sp * SEGCAP + t] : 0;
    }

    for (int i = t; i < NBUCK / 4; i += TPB2) ((int4*)hist)[i] = make_int4(0, 0, 0, 0);
    if (t == 0) s_csel = 0;
    __syncthreads();
#pragma unroll
    for (int sp = 0; sp < SPLITS; ++sp) {
        if (t < csp[sp]) atomicAdd(&hist[(unsigned)(rk[sp] >> 52)], 1);
    }
    __syncthreads();

    // block suffix scan over 8-bucket groups via wave shuffles
    const int G = NBUCK / TPB2;   // 8
    int ps = 0;
#pragma unroll
    for (int p = 0; p < G; ++p) ps += hist[t * G + p];
    int sfx = wave_incl_suffix(ps, lane);
    if (lane == 0) wtot[wid] = sfx;
    __syncthreads();
    int hi = 0;
#pragma unroll
    for (int w = 0; w < TPB2 / 64; ++w) if (w > wid) hi += wtot[w];
    const int sinc = sfx + hi;
    {
        int running = sinc - ps;
#pragma unroll
        for (int p = G - 1; p >= 0; --p) {
            int nr = running + hist[t * G + p];
            if (nr >= KSEL && running < KSEL) s_bstar = t * G + p;
            running = nr;
        }
    }
    __syncthreads();
    const unsigned bstar = (unsigned)s_bstar;

    // compact survivors (bucket >= b*) into LDS from registers
#pragma unroll
    for (int sp = 0; sp < SPLITS; ++sp) {
        if (t < csp[sp] && (unsigned)(rk[sp] >> 52) >= bstar) {
            int p = atomicAdd(&s_csel, 1);
            if (p < SORTCAP) buf[p] = rk[sp];
        }
    }
    __syncthreads();
    const int C = min(s_csel, SORTCAP);
    int P = KSEL;
    while (P < C) P <<= 1;                 // pow2 in [256, 2048]
    for (int i = C + t; i < P; i += TPB2) buf[i] = 0;   // pad (sinks in desc sort)
    __syncthreads();

    // bitonic sort descending on uint64 keys
    for (int kk = 2; kk <= P; kk <<= 1) {
        for (int j = kk >> 1; j > 0; j >>= 1) {
            for (int i = t; i < P; i += TPB2) {
                int ixj = i ^ j;
                if (ixj > i) {
                    ull a = buf[i], d = buf[ixj];
                    bool up = (i & kk) == 0;
                    bool sw = up ? (a < d) : (a > d);
                    if (sw) { buf[i] = d; buf[ixj] = a; }
                }
            }
            __syncthreads();
        }
    }

    // emit in parallel: t<256 gathers ROI rows, 256<=t<512 writes scores
    if (t < KSEL) {
        ull k = buf[t];
        int idx = NANCH - 1 - (int)(unsigned)(k & 0xffffffffull);
        float4 r = ((const float4*)roi)[(size_t)b * NANCH + idx];
        ((float4*)out_roi)[b * KSEL + t] = r;
    } else if (t < 2 * KSEL) {
        const int tt = t - KSEL;
        ull k = buf[tt];
        out_score[b * KSEL + tt] = f_of_ord((unsigned)(k >> 32));
    }
}

// ---------------------------------------------------------------- launch
extern "C" void kernel_launch(void* const* d_in, const int* in_sizes, int n_in,
                              void* d_out, int out_size, void* d_ws, size_t ws_size,
                              hipStream_t stream)
{
    const float* score = (const float*)d_in[0];   // [B, N] fp32
    const float* roi   = (const float*)d_in[1];   // [B, N, 4] fp32
    float* out_roi   = (float*)d_out;                            // [B, K, 4]
    float* out_score = (float*)d_out + (size_t)BATCH * KSEL * 4; // [B, K]

    int* cnt  = (int*)d_ws;                       // [BATCH][SPLITS] counts (8 KB)
    ull* cand = (ull*)((char*)d_ws + 8192);       // [BATCH][CAPMAX] keys (8 MB)

    // no memset: per-(batch,split) counts are written unconditionally
    topk_stage1<<<dim3(SPLITS, BATCH), TPB, 0, stream>>>(score, cand, cnt);
    topk_stage2<<<BATCH, TPB2, 0, stream>>>(cand, cnt, roi, out_roi, out_score);
}

// Round 3
// 353.331 us; speedup vs baseline: 1.0484x; 1.0086x over previous
//
#include <hip/hip_runtime.h>
#include <stdint.h>

// ROISelect: B=128 batches, N=131072 anchors, K=256 top-k + ROI gather.
// Single HBM pass over score. Stage1: per-(batch,split) block stages its 8K
// chunk as order-preserving uint32 in registers, LDS-histograms top 12 bits,
// finds local top-256 bucket threshold, compacts candidate keys
// (ord<<32 | N-1-idx) into a FIXED per-split segment of global scratch and
// writes its exact count (no zero-init, no memset, no global atomics).
// Stage2 (512 thr): per-batch block register-stages the 16 segments,
// re-selects survivors via LDS histogram + scan-compact, then a HYBRID
// register/shuffle bitonic sort (j<64 via shfl_xor, j>=64 via LDS; 12
// barriers instead of 45), gathers ROI rows straight from registers.
//
// THEORY JOURNAL: measured dur_us includes 2x 1GiB harness workspace-poison
// fills (~163us each @82-84% HBM peak — the entire rocprof top-5; 2*163+30
// = 356 measured, arithmetic closes). Controllable share ~30us vs ~15us
// structural floor (stage1 64MiB read=10.2us @6.3TB/s + stage2 ~3 + gaps).

#define BATCH   128
#define NANCH   131072
#define KSEL    256
#define SPLITS  16
#define CHUNK   (NANCH / SPLITS)     // 8192
#define TPB     256
#define V4PT    (CHUNK / TPB / 4)    // 8 uint4 per thread (32 values)
#define NBUCK   4096
#define CAPMAX  8192                 // per-batch candidate capacity (keys)
#define SEGCAP  (CAPMAX / SPLITS)    // 512 per split (expect ~380 used)
#define SORTCAP 2048
#define TPB2    512

typedef unsigned long long ull;

__device__ __forceinline__ unsigned ord_of(float f) {
    unsigned u = __float_as_uint(f);
    // monotone map: larger float -> larger uint
    return (u & 0x80000000u) ? ~u : (u | 0x80000000u);
}
__device__ __forceinline__ float f_of_ord(unsigned o) {
    unsigned u = (o & 0x80000000u) ? (o ^ 0x80000000u) : ~o;
    return __uint_as_float(u);
}

// wave64 inclusive prefix sum (lane i gets sum of lanes [0,i])
__device__ __forceinline__ int wave_incl_prefix(int v, int lane) {
#pragma unroll
    for (int off = 1; off < 64; off <<= 1) {
        int n = __shfl_up(v, off);
        if (lane >= off) v += n;
    }
    return v;
}
// wave64 inclusive suffix sum (lane i gets sum of lanes [i,63])
__device__ __forceinline__ int wave_incl_suffix(int v, int lane) {
#pragma unroll
    for (int off = 1; off < 64; off <<= 1) {
        int n = __shfl_down(v, off);
        if (lane + off < 64) v += n;
    }
    return v;
}
// 64-bit xor-shuffle built from two 32-bit shuffles
__device__ __forceinline__ ull shfl_xor64(ull x, int mask) {
    int lo = __shfl_xor((int)(unsigned)x, mask);
    int hi = __shfl_xor((int)(unsigned)(x >> 32), mask);
    return ((ull)(unsigned)hi << 32) | (unsigned)lo;
}

// ---------------------------------------------------------------- stage 1
__global__ __launch_bounds__(TPB) void topk_stage1(
    const float* __restrict__ score, ull* __restrict__ cand,
    int* __restrict__ cnt)
{
    __shared__ int hist[NBUCK];
    __shared__ int wtot[TPB / 64];
    __shared__ int s_bstar;

    const int t    = threadIdx.x;
    const int lane = t & 63;
    const int wid  = t >> 6;
    const int sp   = blockIdx.x;   // split within batch row
    const int b    = blockIdx.y;   // batch

    // coalesced float4 loads; convert to ordered uint ONCE
    const float4* src = (const float4*)(score + (size_t)b * NANCH + (size_t)sp * CHUNK);
    uint4 v[V4PT];
#pragma unroll
    for (int i = 0; i < V4PT; ++i) {
        float4 f = src[i * TPB + t];
        v[i].x = ord_of(f.x); v[i].y = ord_of(f.y);
        v[i].z = ord_of(f.z); v[i].w = ord_of(f.w);
    }

    for (int i = t; i < NBUCK / 4; i += TPB) ((int4*)hist)[i] = make_int4(0, 0, 0, 0);
    __syncthreads();

#pragma unroll
    for (int i = 0; i < V4PT; ++i) {
        atomicAdd(&hist[v[i].x >> 20], 1);
        atomicAdd(&hist[v[i].y >> 20], 1);
        atomicAdd(&hist[v[i].z >> 20], 1);
        atomicAdd(&hist[v[i].w >> 20], 1);
    }
    __syncthreads();

    // per-thread partial over its 16-bucket group, block suffix scan via
    // wave shuffles (2 barriers total)
    int ps = 0;
#pragma unroll
    for (int p = 0; p < 16; ++p) ps += hist[t * 16 + p];
    int sfx = wave_incl_suffix(ps, lane);
    if (lane == 0) wtot[wid] = sfx;     // wave total
    __syncthreads();
    int hi = 0;
#pragma unroll
    for (int w = 0; w < TPB / 64; ++w) if (w > wid) hi += wtot[w];
    const int sinc = sfx + hi;          // inclusive suffix over block groups

    // largest bucket b* with suffix-count S(b*) >= KSEL  (unique crossing)
    {
        int running = sinc - ps;        // suffix of groups strictly above mine
#pragma unroll
        for (int p = 15; p >= 0; --p) {
            int nr = running + hist[t * 16 + p];
            if (nr >= KSEL && running < KSEL) s_bstar = t * 16 + p;
            running = nr;
        }
    }
    __syncthreads();
    const unsigned thr = (unsigned)s_bstar << 20;   // qualify iff ordered >= thr

    // count qualifiers per thread
    int qc = 0;
#pragma unroll
    for (int i = 0; i < V4PT; ++i) {
        qc += (v[i].x >= thr);
        qc += (v[i].y >= thr);
        qc += (v[i].z >= thr);
        qc += (v[i].w >= thr);
    }
    // block inclusive prefix scan via wave shuffles
    int pfx = wave_incl_prefix(qc, lane);
    if (lane == 63) wtot[wid] = pfx;    // wave total (s_bstar barrier guards reuse)
    __syncthreads();
    int lo = 0, total = 0;
#pragma unroll
    for (int w = 0; w < TPB / 64; ++w) {
        total += wtot[w];
        if (w < wid) lo += wtot[w];
    }
    // per-(batch,split) count: written unconditionally -> no zero-init needed
    if (t == 0) cnt[b * SPLITS + sp] = (total < SEGCAP) ? total : SEGCAP;

    int pos = lo + pfx - qc;            // exclusive position within segment
    ull* cb = cand + (size_t)b * CAPMAX + (size_t)sp * SEGCAP;
    const int nbase = sp * CHUNK;
#pragma unroll
    for (int i = 0; i < V4PT; ++i) {
        const int n0 = nbase + 4 * (i * TPB + t);
        unsigned o;
        o = v[i].x;
        if (o >= thr && pos < SEGCAP) { cb[pos++] = ((ull)o << 32) | (unsigned)(NANCH - 1 - n0); }
        o = v[i].y;
        if (o >= thr && pos < SEGCAP) { cb[pos++] = ((ull)o << 32) | (unsigned)(NANCH - 2 - n0); }
        o = v[i].z;
        if (o >= thr && pos < SEGCAP) { cb[pos++] = ((ull)o << 32) | (unsigned)(NANCH - 3 - n0); }
        o = v[i].w;
        if (o >= thr && pos < SEGCAP) { cb[pos++] = ((ull)o << 32) | (unsigned)(NANCH - 4 - n0); }
    }
}

// ---------------------------------------------------------------- stage 2
__global__ __launch_bounds__(TPB2) void topk_stage2(
    const ull* __restrict__ cand, const int* __restrict__ cnt,
    const float* __restrict__ roi, float* __restrict__ out_roi,
    float* __restrict__ out_score)
{
    __shared__ int hist[NBUCK];
    __shared__ int wtot[TPB2 / 64];
    __shared__ ull buf[SORTCAP];
    __shared__ int s_bstar;

    const int t    = threadIdx.x;
    const int lane = t & 63;
    const int wid  = t >> 6;
    const int b    = blockIdx.x;
    const ull* cb  = cand + (size_t)b * CAPMAX;

    // register-stage all 16 segments: exactly 1 coalesced load / thread / seg
    // (fully unrolled -> static register indexing, no scratch)
    int csp[SPLITS];
    ull rk[SPLITS];
#pragma unroll
    for (int sp = 0; sp < SPLITS; ++sp) {
        int c = cnt[b * SPLITS + sp];          // uniform address -> s_load
        csp[sp] = (c < SEGCAP) ? c : SEGCAP;
        rk[sp] = (t < csp[sp]) ? cb[sp * SEGCAP + t] : 0;
    }

    for (int i = t; i < NBUCK / 4; i += TPB2) ((int4*)hist)[i] = make_int4(0, 0, 0, 0);
    __syncthreads();
#pragma unroll
    for (int sp = 0; sp < SPLITS; ++sp) {
        if (t < csp[sp]) atomicAdd(&hist[(unsigned)(rk[sp] >> 52)], 1);
    }
    __syncthreads();

    // block suffix scan over 8-bucket groups via wave shuffles
    const int G = NBUCK / TPB2;   // 8
    int ps = 0;
#pragma unroll
    for (int p = 0; p < G; ++p) ps += hist[t * G + p];
    int sfx = wave_incl_suffix(ps, lane);
    if (lane == 0) wtot[wid] = sfx;
    __syncthreads();
    int hi = 0;
#pragma unroll
    for (int w = 0; w < TPB2 / 64; ++w) if (w > wid) hi += wtot[w];
    const int sinc = sfx + hi;
    {
        int running = sinc - ps;
#pragma unroll
        for (int p = G - 1; p >= 0; --p) {
            int nr = running + hist[t * G + p];
            if (nr >= KSEL && running < KSEL) s_bstar = t * G + p;
            running = nr;
        }
    }
    __syncthreads();
    const unsigned bstar = (unsigned)s_bstar;

    // scan-based compact of survivors (bucket >= b*) into LDS buf:
    // no single-address atomic contention, deterministic positions
    int qc = 0;
#pragma unroll
    for (int sp = 0; sp < SPLITS; ++sp)
        qc += (t < csp[sp] && (unsigned)(rk[sp] >> 52) >= bstar) ? 1 : 0;
    int pfx = wave_incl_prefix(qc, lane);
    if (lane == 63) wtot[wid] = pfx;    // reuse guarded by s_bstar barrier
    __syncthreads();
    int lo = 0, Ctot = 0;
#pragma unroll
    for (int w = 0; w < TPB2 / 64; ++w) {
        Ctot += wtot[w];
        if (w < wid) lo += wtot[w];
    }
    int pos = lo + pfx - qc;            // exclusive position
#pragma unroll
    for (int sp = 0; sp < SPLITS; ++sp) {
        if (t < csp[sp] && (unsigned)(rk[sp] >> 52) >= bstar) {
            if (pos < SORTCAP) buf[pos] = rk[sp];
            ++pos;
        }
    }
    __syncthreads();
    const int C = (Ctot < SORTCAP) ? Ctot : SORTCAP;   // C >= KSEL by construction
    int P = KSEL;
    while (P < C) P <<= 1;                 // pow2 in [256, 2048]
    for (int i = C + t; i < P; i += TPB2) buf[i] = 0;  // pad (sinks in desc sort)
    __syncthreads();

    if (P <= TPB2) {
        // fast path (common: P in {256, 512}): one key per thread in a
        // register; j<64 exchange steps via shfl_xor (no barrier), only
        // j>=64 steps round-trip LDS. 12 barriers max vs 45.
        ull r = (t < P) ? buf[t] : 0;
        for (int kk = 2; kk <= P; kk <<= 1) {
            for (int j = kk >> 1; j > 0; j >>= 1) {
                if (j >= 64) {
                    if (t < P) buf[t] = r;
                    __syncthreads();
                    if (t < P) {
                        ull o = buf[t ^ j];
                        bool keepMax = (((t & kk) == 0) == ((t & j) == 0));
                        r = keepMax ? (r > o ? r : o) : (r < o ? r : o);
                    }
                    __syncthreads();
                } else if (t < P) {      // whole waves in/out: P % 64 == 0
                    ull o = shfl_xor64(r, j);
                    bool keepMax = (((t & kk) == 0) == ((t & j) == 0));
                    r = keepMax ? (r > o ? r : o) : (r < o ? r : o);
                }
            }
        }
        // emit straight from registers: thread t holds rank-t key
        if (t < KSEL) {
            int idx = NANCH - 1 - (int)(unsigned)(r & 0xffffffffull);
            out_score[b * KSEL + t] = f_of_ord((unsigned)(r >> 32));
            float4 rr = ((const float4*)roi)[(size_t)b * NANCH + idx];
            ((float4*)out_roi)[b * KSEL + t] = rr;
        }
    } else {
        // generic LDS bitonic fallback (rare: C > 512)
        for (int kk = 2; kk <= P; kk <<= 1) {
            for (int j = kk >> 1; j > 0; j >>= 1) {
                for (int i = t; i < P; i += TPB2) {
                    int ixj = i ^ j;
                    if (ixj > i) {
                        ull a = buf[i], d = buf[ixj];
                        bool up = (i & kk) == 0;
                        bool sw = up ? (a < d) : (a > d);
                        if (sw) { buf[i] = d; buf[ixj] = a; }
                    }
                }
                __syncthreads();
            }
        }
        if (t < KSEL) {
            ull k = buf[t];
            int idx = NANCH - 1 - (int)(unsigned)(k & 0xffffffffull);
            out_score[b * KSEL + t] = f_of_ord((unsigned)(k >> 32));
            float4 rr = ((const float4*)roi)[(size_t)b * NANCH + idx];
            ((float4*)out_roi)[b * KSEL + t] = rr;
        }
    }
}

// ---------------------------------------------------------------- launch
extern "C" void kernel_launch(void* const* d_in, const int* in_sizes, int n_in,
                              void* d_out, int out_size, void* d_ws, size_t ws_size,
                              hipStream_t stream)
{
    const float* score = (const float*)d_in[0];   // [B, N] fp32
    const float* roi   = (const float*)d_in[1];   // [B, N, 4] fp32
    float* out_roi   = (float*)d_out;                            // [B, K, 4]
    float* out_score = (float*)d_out + (size_t)BATCH * KSEL * 4; // [B, K]

    int* cnt  = (int*)d_ws;                       // [BATCH][SPLITS] counts (8 KB)
    ull* cand = (ull*)((char*)d_ws + 8192);       // [BATCH][CAPMAX] keys (8 MB)

    // no memset: per-(batch,split) counts are written unconditionally
    topk_stage1<<<dim3(SPLITS, BATCH), TPB, 0, stream>>>(score, cand, cnt);
    topk_stage2<<<BATCH, TPB2, 0, stream>>>(cand, cnt, roi, out_roi, out_score);
}